// Round 17
// baseline (2355.690 us; speedup 1.0000x reference)
//
#include <hip/hip_runtime.h>
#include <math.h>

#define BD 16384            // B*D
#define TT 512
#define KDIM 1024
#define NDIM 1024
#define GEMM_M 8192
#define PANEL_Q 320         // OpenBLAS SGEMM_DEFAULT_Q (SKYLAKEX/COOPERLAKE AVX512 path)
#define LOGE2F 0.69314718246459960938f

// ===========================================================================
// Scan transcendentals: ROCm native f32 libm — FROZEN (r7-r16 passed).
// Compound arithmetic uses __fadd_rn/__fmul_rn/__fsub_rn to forbid FMA
// contraction.
// ===========================================================================
__device__ __forceinline__ float np_expf(float x)   { return expf(x); }
__device__ __forceinline__ float np_logf(float x)   { return logf(x); }
__device__ __forceinline__ float np_log1pf(float x) { return log1pf(x); }

__device__ __forceinline__ float np_softplus(float v) {
    const float e  = np_expf(-fabsf(v));
    const float l1 = np_log1pf(e);
    const float r  = __fadd_rn(fmaxf(v, 0.0f), l1);
    return (v == 0.0f) ? LOGE2F : r;      // npy_logaddexpf x==y special case
}

// signed_log_add with select-before-log1p (bit-identical; r15/r16 passed).
__device__ __forceinline__ void np_sla(float la, float sa, float lb, float sb,
                                       float& lo, float& so) {
    bool az = la <= -39.0f;                  // LOG_ZERO + 1
    bool bz = lb <= -39.0f;
    float mx = fmaxf(la, lb);
    float mn = fminf(la, lb);
    float diff = __fsub_rn(mn, mx);
    bool amax = la >= lb;
    float smax = amax ? sa : sb;
    float smin = amax ? sb : sa;
    bool same = __fmul_rn(smax, smin) > 0.0f;
    float ed = np_expf(diff);
    float arg = same ? ed : -fminf(ed, 0.9999f);
    float l = __fadd_rn(mx, np_log1pf(arg));
    float s = smax;
    l = az ? lb : l;  s = az ? sb : s;
    bool bo = bz && !az;
    l = bo ? la : l;  s = bo ? sa : s;
    lo = l; so = s;
}

// ===========================================================================
// OpenBLAS-sgemm-exact NT-GEMM. Per-element arithmetic FROZEN (r7-r16):
// single-accumulator FMA chain, k strictly ascending, Q=320 panels
// {320,320,320,64}, partials folded left-assoc into C, bias one separate add.
// NEW schedule: 128x128 block tile, 8x8/thread, but panel partials fold into
// C via same-block global RMW — executes the BLAS chain LITERALLY
// (C=p1; C+=p2; C+=p3; C+=p4; then +bias) — so `tot` registers vanish:
// acc-only = 64 VGPR -> 4 waves/SIMD co-resident (r15's 8x8 had 1), at
// 2.0 FLOP per LDS byte (vs r16's 1.33, which was the LDS-BW wall).
// All ds_read_b128 stride-4 (2-way aliasing, free).
// ===========================================================================
__global__ __launch_bounds__(256, 4) void gemm_blas(
    const float* __restrict__ x,
    const float* __restrict__ Wa, const float* __restrict__ Wx, const float* __restrict__ Wd,
    const float* __restrict__ ba, const float* __restrict__ bx, const float* __restrict__ bd,
    float* __restrict__ out_a, float* __restrict__ out_x, float* __restrict__ out_d)
{
    const int z = blockIdx.z;
    const float* W    = (z == 0) ? Wa : (z == 1) ? Wx : Wd;
    const float* bias = (z == 0) ? ba : (z == 1) ? bx : bd;
    float* out        = (z == 0) ? out_a : (z == 1) ? out_x : out_d;

    const int m0 = blockIdx.x * 128;
    const int n0 = blockIdx.y * 128;

    __shared__ float As[16][132];  // [k in tile][m]
    __shared__ float Bs[16][132];  // [k in tile][n]

    const int tid = threadIdx.x;
    const int lr = tid >> 2;       // 0..63 staging row
    const int lc = tid & 3;        // float4 column within BK=16
    const int ty = tid >> 4;       // 0..15 -> rows ty*4+i, 64+ty*4+i
    const int tx = tid & 15;       // 0..15 -> cols tx*4+j, 64+tx*4+j

    const float* Ap = x + (size_t)(m0 + lr) * KDIM + lc * 4;
    const float* Bp = W + (size_t)(n0 + lr) * KDIM + lc * 4;

    float bj[8];
    #pragma unroll
    for (int j = 0; j < 4; ++j) {
        bj[j]     = bias[n0 + tx * 4 + j];
        bj[4 + j] = bias[n0 + 64 + tx * 4 + j];
    }

    for (int p = 0; p < 4; ++p) {                  // K panels {320,320,320,64}
        const int k0 = p * PANEL_Q;
        const int k1 = (p == 3) ? KDIM : (k0 + PANEL_Q);

        float acc[8][8];                           // current panel FMA chain
        #pragma unroll
        for (int i = 0; i < 8; ++i)
            #pragma unroll
            for (int j = 0; j < 8; ++j) acc[i][j] = 0.0f;

        float4 aR0 = *(const float4*)(Ap + k0);
        float4 aR1 = *(const float4*)(Ap + (size_t)64 * KDIM + k0);
        float4 bR0 = *(const float4*)(Bp + k0);
        float4 bR1 = *(const float4*)(Bp + (size_t)64 * KDIM + k0);

        for (int kt = k0; kt < k1; kt += 16) {
            __syncthreads();
            {
                const float* a0 = (const float*)&aR0;
                const float* a1 = (const float*)&aR1;
                const float* b0 = (const float*)&bR0;
                const float* b1 = (const float*)&bR1;
                #pragma unroll
                for (int c = 0; c < 4; ++c) {
                    As[lc * 4 + c][lr]      = a0[c];
                    As[lc * 4 + c][lr + 64] = a1[c];
                    Bs[lc * 4 + c][lr]      = b0[c];
                    Bs[lc * 4 + c][lr + 64] = b1[c];
                }
            }
            __syncthreads();
            if (kt + 16 < k1) {    // prefetch next K-slab under compute
                aR0 = *(const float4*)(Ap + kt + 16);
                aR1 = *(const float4*)(Ap + (size_t)64 * KDIM + kt + 16);
                bR0 = *(const float4*)(Bp + kt + 16);
                bR1 = *(const float4*)(Bp + (size_t)64 * KDIM + kt + 16);
            }
            #pragma unroll
            for (int kk = 0; kk < 16; ++kk) {      // k strictly ascending
                const float4 a0 = *(const float4*)&As[kk][ty * 4];
                const float4 a1 = *(const float4*)&As[kk][64 + ty * 4];
                const float4 b0 = *(const float4*)&Bs[kk][tx * 4];
                const float4 b1 = *(const float4*)&Bs[kk][64 + tx * 4];
                const float av[8] = {a0.x, a0.y, a0.z, a0.w, a1.x, a1.y, a1.z, a1.w};
                const float bv[8] = {b0.x, b0.y, b0.z, b0.w, b1.x, b1.y, b1.z, b1.w};
                #pragma unroll
                for (int i = 0; i < 8; ++i)
                    #pragma unroll
                    for (int j = 0; j < 8; ++j)
                        acc[i][j] = __fmaf_rn(av[i], bv[j], acc[i][j]);
            }
        }

        // Fold this panel into C (left-assoc chain, exactly the BLAS order).
        #pragma unroll
        for (int h = 0; h < 2; ++h) {              // row halves
            #pragma unroll
            for (int i = 0; i < 4; ++i) {
                const int mi = h * 4 + i;
                float* rp = out + (size_t)(m0 + h * 64 + ty * 4 + i) * NDIM + n0;
                #pragma unroll
                for (int q = 0; q < 2; ++q) {      // col halves
                    float* op = rp + q * 64 + tx * 4;
                    float4 v;
                    if (p == 0) {
                        v.x = acc[mi][q * 4 + 0]; v.y = acc[mi][q * 4 + 1];
                        v.z = acc[mi][q * 4 + 2]; v.w = acc[mi][q * 4 + 3];
                    } else {
                        const float4 o = *(const float4*)op;
                        v.x = __fadd_rn(o.x, acc[mi][q * 4 + 0]);
                        v.y = __fadd_rn(o.y, acc[mi][q * 4 + 1]);
                        v.z = __fadd_rn(o.z, acc[mi][q * 4 + 2]);
                        v.w = __fadd_rn(o.w, acc[mi][q * 4 + 3]);
                    }
                    if (p == 3) {                  // bias as one separate add
                        v.x = __fadd_rn(v.x, bj[q * 4 + 0]);
                        v.y = __fadd_rn(v.y, bj[q * 4 + 1]);
                        v.z = __fadd_rn(v.z, bj[q * 4 + 2]);
                        v.w = __fadd_rn(v.w, bj[q * 4 + 3]);
                    }
                    *(float4*)op = v;
                }
            }
        }
    }
}

// ===========================================================================
// f32 scan — byte-for-byte r16 (passed): 3-wave structure (producer /
// consumer / writer), consumer 6 libm bodies/step via select-before-log1p.
// ===========================================================================
__device__ __forceinline__ void gl_lds(const float* g, float* l) {
    __builtin_amdgcn_global_load_lds(
        (const __attribute__((address_space(1))) void*)g,
        (__attribute__((address_space(3))) void*)l, 4, 0, 0);
}

#define WAITVM(N) do {                                                   \
    asm volatile("s_waitcnt vmcnt(" #N ")" ::: "memory");                \
    __builtin_amdgcn_sched_barrier(0); } while (0)

__global__ __launch_bounds__(192, 1) void scan_kernel(
    float* __restrict__ log_h, float* __restrict__ sign_h, float* __restrict__ h_lin,
    const float* __restrict__ log_r_h, const float* __restrict__ sign_r_h)
{
    __shared__ float Xr[4][5][4][64];   // [slot][a,li,si,ld,lm][u][lane]  20 KB
    __shared__ float Or[4][2][4][64];   // [slot][lhn,shn][u][lane]         8 KB
    __shared__ float Rr[4][12][64];     // raw ring (producer only)        12 KB

    const int wv = threadIdx.x >> 6;
    const int ln = threadIdx.x & 63;
    const int idx = blockIdx.x * 64 + ln;

#define ISSUE_LOADS(GG, SL) do {                                         \
    const int _b = (GG) * 4;                                             \
    _Pragma("unroll")                                                    \
    for (int u = 0; u < 4; ++u) {                                        \
        gl_lds(h_lin  + (size_t)(_b + u) * BD + idx,     &Rr[SL][u * 3 + 0][0]); \
        gl_lds(log_h  + (size_t)(_b + u + 1) * BD + idx, &Rr[SL][u * 3 + 1][0]); \
        gl_lds(sign_h + (size_t)(_b + u + 1) * BD + idx, &Rr[SL][u * 3 + 2][0]); \
    } } while (0)

#define XFORM_TO(GG) do {                                                \
    const int _s = (GG) & 3;                                             \
    _Pragma("unroll")                                                    \
    for (int u = 0; u < 4; ++u) {                                        \
        const float araw = Rr[_s][u * 3 + 0][ln];                        \
        const float lin  = Rr[_s][u * 3 + 1][ln];                        \
        const float dr   = Rr[_s][u * 3 + 2][ln];                        \
        Xr[_s][0][u][ln] = __fadd_rn(1.0f, np_softplus(araw));           \
        const float ax = fabsf(lin);                                     \
        Xr[_s][1][u][ln] = (ax > 1e-10f) ? np_logf(fmaxf(ax, 1e-10f))    \
                                         : -40.0f;                       \
        Xr[_s][2][u][ln] = (lin < 0.0f) ? -1.0f : 1.0f;                  \
        const float e  = np_expf(-fabsf(dr));                            \
        const float l1 = np_log1pf(e);                                   \
        const float big = -__fadd_rn(fabsf(dr), l1);                     \
        const float sml = -l1;                                           \
        const float ld0 = (dr > 0.0f) ? sml : big;                       \
        const float lm0 = (dr > 0.0f) ? big : sml;                       \
        Xr[_s][3][u][ln] = (dr == 0.0f) ? -LOGE2F : ld0;                 \
        Xr[_s][4][u][ln] = (dr == 0.0f) ? -LOGE2F : lm0;                 \
    } } while (0)

#define WRITE_GROUP(GG) do {                                             \
    const int _s = (GG) & 3;                                             \
    _Pragma("unroll")                                                    \
    for (int u = 0; u < 4; ++u) {                                        \
        const int t = (GG) * 4 + u;                                      \
        const float lhn = Or[_s][0][u][ln];                              \
        const float shn = Or[_s][1][u][ln];                              \
        const float res = __fmul_rn(shn, np_expf(fminf(lhn, 20.0f)));    \
        const float h = (lhn > -39.0f) ? res : 0.0f;                     \
        log_h[(size_t)(t + 1) * BD + idx] = lhn;                         \
        sign_h[(size_t)(t + 1) * BD + idx] = shn;                        \
        h_lin[(size_t)t * BD + idx] = h;                                 \
    } } while (0)

    // ---- prologue ----
    float lrh = 0.0f, srh = 0.0f;
    if (wv == 1) {
        const int d = idx & 1023;
        lrh = log_r_h[d];
        srh = sign_r_h[d];
    } else if (wv == 0) {
        ISSUE_LOADS(0, 0);
        ISSUE_LOADS(1, 1);
        WAITVM(0);
        XFORM_TO(0);
        XFORM_TO(1);
        ISSUE_LOADS(2, 2);          // in flight across the barrier
    } else {
        log_h[idx] = -40.0f;        // row 0
        sign_h[idx] = 1.0f;
    }
    __syncthreads();

    float lhp = -40.0f, shp = 1.0f;

    for (int g = 0; g < 128; ++g) {
        if (wv == 0) {
            // FIFO before wait: loads(g+2)[12 old] | loads(g+3)[12 new]
            const int gl = (g + 3 < 128) ? g + 3 : 127;   // dead-slot clamp
            ISSUE_LOADS(gl, (g + 3) & 3);
            WAITVM(12);                                    // loads(g+2) done
            if (g + 2 < 128) XFORM_TO(g + 2);
        } else if (wv == 1) {
            const int s = g & 3;
            float xa[4], xli[4], xsi[4], xld[4], xlm[4];
            #pragma unroll
            for (int u = 0; u < 4; ++u) {
                xa[u]  = Xr[s][0][u][ln];
                xli[u] = Xr[s][1][u][ln];
                xsi[u] = Xr[s][2][u][ln];
                xld[u] = Xr[s][3][u][ln];
                xlm[u] = Xr[s][4][u][ln];
            }
            #pragma unroll
            for (int u = 0; u < 4; ++u) {       // serial chain (bit-frozen)
                const float log_rh  = __fadd_rn(lrh, lhp);
                const float sign_rh = __fmul_rn(srh, shp);
                float lv, sv;
                np_sla(log_rh, sign_rh, xli[u], xsi[u], lv, sv);
                const float tt = __fmul_rn(xa[u], lv);
                const float log_cand = -np_softplus(-tt);
                float lhn, shn;
                np_sla(__fadd_rn(xlm[u], lhp), shp,
                       __fadd_rn(xld[u], log_cand), sv, lhn, shn);
                Or[s][0][u][ln] = lhn;
                Or[s][1][u][ln] = shn;
                lhp = lhn; shp = shn;
            }
        } else {
            if (g > 0) WRITE_GROUP(g - 1);
        }
        __syncthreads();
    }
    if (wv == 2) WRITE_GROUP(127);   // last loop barrier orders Or[3]

#undef ISSUE_LOADS
#undef XFORM_TO
#undef WRITE_GROUP
}

// ===========================================================================
extern "C" void kernel_launch(void* const* d_in, const int* in_sizes, int n_in,
                              void* d_out, int out_size, void* d_ws, size_t ws_size,
                              hipStream_t stream) {
    const float* x        = (const float*)d_in[0];
    const float* W_x      = (const float*)d_in[1];
    const float* W_alpha  = (const float*)d_in[2];
    const float* W_delta  = (const float*)d_in[3];
    const float* b        = (const float*)d_in[4];
    const float* b_alpha  = (const float*)d_in[5];
    const float* b_delta  = (const float*)d_in[6];
    const float* log_r_h  = (const float*)d_in[7];
    const float* sign_r_h = (const float*)d_in[8];

    float* out    = (float*)d_out;
    float* log_h  = out;                            // [513, BD]
    float* sign_h = out + (size_t)513 * BD;         // [513, BD]
    float* h_lin  = out + (size_t)2 * 513 * BD;     // [512, BD]

    dim3 ggrid(GEMM_M / 128, NDIM / 128, 3);
    gemm_blas<<<ggrid, dim3(256), 0, stream>>>(
        x, W_alpha, W_x, W_delta, b_alpha, b, b_delta,
        h_lin, log_h + BD, sign_h + BD);

    scan_kernel<<<dim3(BD / 64), dim3(192), 0, stream>>>(
        log_h, sign_h, h_lin, log_r_h, sign_r_h);
}

// Round 18
// 1119.362 us; speedup vs baseline: 2.1045x; 2.1045x over previous
//
#include <hip/hip_runtime.h>
#include <math.h>

#define BD 16384            // B*D
#define TT 512
#define KDIM 1024
#define NDIM 1024
#define GEMM_M 8192
#define PANEL_Q 320         // OpenBLAS SGEMM_DEFAULT_Q (SKYLAKEX/COOPERLAKE AVX512 path)
#define LOGE2F 0.69314718246459960938f

// ===========================================================================
// Scan transcendentals: ROCm native f32 libm — FROZEN (r7-r16 passed).
// Compound arithmetic uses __fadd_rn/__fmul_rn/__fsub_rn to forbid FMA
// contraction.
// ===========================================================================
__device__ __forceinline__ float np_expf(float x)   { return expf(x); }
__device__ __forceinline__ float np_logf(float x)   { return logf(x); }
__device__ __forceinline__ float np_log1pf(float x) { return log1pf(x); }

__device__ __forceinline__ float np_softplus(float v) {
    const float e  = np_expf(-fabsf(v));
    const float l1 = np_log1pf(e);
    const float r  = __fadd_rn(fmaxf(v, 0.0f), l1);
    return (v == 0.0f) ? LOGE2F : r;      // npy_logaddexpf x==y special case
}

// signed_log_add with select-before-log1p (bit-identical; r15/r16 passed).
__device__ __forceinline__ void np_sla(float la, float sa, float lb, float sb,
                                       float& lo, float& so) {
    bool az = la <= -39.0f;                  // LOG_ZERO + 1
    bool bz = lb <= -39.0f;
    float mx = fmaxf(la, lb);
    float mn = fminf(la, lb);
    float diff = __fsub_rn(mn, mx);
    bool amax = la >= lb;
    float smax = amax ? sa : sb;
    float smin = amax ? sb : sa;
    bool same = __fmul_rn(smax, smin) > 0.0f;
    float ed = np_expf(diff);
    float arg = same ? ed : -fminf(ed, 0.9999f);
    float l = __fadd_rn(mx, np_log1pf(arg));
    float s = smax;
    l = az ? lb : l;  s = az ? sb : s;
    bool bo = bz && !az;
    l = bo ? la : l;  s = bo ? sa : s;
    lo = l; so = s;
}

// ===========================================================================
// OpenBLAS-sgemm-exact NT-GEMM. Per-element arithmetic FROZEN (r7-r16):
// single-accumulator FMA chain, k strictly ascending, Q=320 panel folds
// {320,320,320,64} left-assoc in REGISTERS (r16 structure — r17's RMW fold
// thrashed L2 and is reverted), bias as one separate f32 add.
// Memory schedule: 128x64 block tile, 8x4/thread, BK=32 with DOUBLE-BUFFERED
// LDS -> ONE barrier per kt (32 total vs r16's 128). Global prefetch for
// kt+1 issues before the 32-kk compute. All ds_read_b128 stride-4 (2-way
// aliasing, free). Panel boundaries 320/640/960 are multiples of 32.
// ===========================================================================
__global__ __launch_bounds__(256, 4) void gemm_blas(
    const float* __restrict__ x,
    const float* __restrict__ Wa, const float* __restrict__ Wx, const float* __restrict__ Wd,
    const float* __restrict__ ba, const float* __restrict__ bx, const float* __restrict__ bd,
    float* __restrict__ out_a, float* __restrict__ out_x, float* __restrict__ out_d)
{
    const int z = blockIdx.z;
    const float* W    = (z == 0) ? Wa : (z == 1) ? Wx : Wd;
    const float* bias = (z == 0) ? ba : (z == 1) ? bx : bd;
    float* out        = (z == 0) ? out_a : (z == 1) ? out_x : out_d;

    const int m0 = blockIdx.x * 128;
    const int n0 = blockIdx.y * 64;

    __shared__ float As[2][32][132];   // [buf][k][m]  33.8 KB
    __shared__ float Bs[2][32][68];    // [buf][k][n]  17.4 KB

    const int tid = threadIdx.x;
    const int lc = tid & 7;        // float4 column within BK=32 (k = lc*4+c)
    const int lr = tid >> 3;       // 0..31 staging row
    const int ty = tid >> 4;       // 0..15 -> rows ty*4+i, 64+ty*4+i
    const int tx = tid & 15;       // 0..15 -> cols tx*4+j

    const float* Ap = x + (size_t)(m0 + lr) * KDIM + lc * 4;
    const float* Bp = W + (size_t)(n0 + lr) * KDIM + lc * 4;

    float4 a4[4], b4[2];           // staged fragments (rows lr+32r / lr+32r)
    #pragma unroll
    for (int r = 0; r < 4; ++r) a4[r] = *(const float4*)(Ap + (size_t)(r * 32) * KDIM);
    #pragma unroll
    for (int r = 0; r < 2; ++r) b4[r] = *(const float4*)(Bp + (size_t)(r * 32) * KDIM);

    float tot[8][4];               // folded finished panels
    float acc[8][4];               // current panel FMA chain
    #pragma unroll
    for (int i = 0; i < 8; ++i)
        #pragma unroll
        for (int j = 0; j < 4; ++j) { tot[i][j] = 0.0f; acc[i][j] = 0.0f; }

    // write buf 0
    {
        #pragma unroll
        for (int c = 0; c < 4; ++c) {
            const float* pa0 = (const float*)&a4[0];
            #pragma unroll
            for (int r = 0; r < 4; ++r)
                As[0][lc * 4 + c][lr + r * 32] = ((const float*)&a4[r])[c];
            #pragma unroll
            for (int r = 0; r < 2; ++r)
                Bs[0][lc * 4 + c][lr + r * 32] = ((const float*)&b4[r])[c];
            (void)pa0;
        }
    }
    __syncthreads();

    int cur = 0;
    for (int kt = 0; kt < KDIM; kt += 32) {
        const bool haveNext = (kt + 32 < KDIM);
        if (haveNext) {            // prefetch next K-slab (consumed post-compute)
            #pragma unroll
            for (int r = 0; r < 4; ++r)
                a4[r] = *(const float4*)(Ap + (size_t)(r * 32) * KDIM + kt + 32);
            #pragma unroll
            for (int r = 0; r < 2; ++r)
                b4[r] = *(const float4*)(Bp + (size_t)(r * 32) * KDIM + kt + 32);
        }
        if (kt == PANEL_Q || kt == 2 * PANEL_Q || kt == 3 * PANEL_Q) {
            #pragma unroll
            for (int i = 0; i < 8; ++i)
                #pragma unroll
                for (int j = 0; j < 4; ++j) {
                    tot[i][j] = __fadd_rn(tot[i][j], acc[i][j]);  // C += panel
                    acc[i][j] = 0.0f;
                }
        }
        #pragma unroll
        for (int kk = 0; kk < 32; ++kk) {          // k strictly ascending
            const float4 A0 = *(const float4*)&As[cur][kk][ty * 4];
            const float4 A1 = *(const float4*)&As[cur][kk][64 + ty * 4];
            const float4 B0 = *(const float4*)&Bs[cur][kk][tx * 4];
            const float av[8] = {A0.x, A0.y, A0.z, A0.w, A1.x, A1.y, A1.z, A1.w};
            const float bv[4] = {B0.x, B0.y, B0.z, B0.w};
            #pragma unroll
            for (int i = 0; i < 8; ++i)
                #pragma unroll
                for (int j = 0; j < 4; ++j)
                    acc[i][j] = __fmaf_rn(av[i], bv[j], acc[i][j]);
        }
        if (haveNext) {
            const int nxt = cur ^ 1;
            #pragma unroll
            for (int c = 0; c < 4; ++c) {
                #pragma unroll
                for (int r = 0; r < 4; ++r)
                    As[nxt][lc * 4 + c][lr + r * 32] = ((const float*)&a4[r])[c];
                #pragma unroll
                for (int r = 0; r < 2; ++r)
                    Bs[nxt][lc * 4 + c][lr + r * 32] = ((const float*)&b4[r])[c];
            }
            __syncthreads();       // single barrier per kt orders both hazards
            cur = nxt;
        }
    }
    #pragma unroll
    for (int i = 0; i < 8; ++i)                    // fold last (64-wide) panel
        #pragma unroll
        for (int j = 0; j < 4; ++j)
            tot[i][j] = __fadd_rn(tot[i][j], acc[i][j]);

    float bj[4];
    #pragma unroll
    for (int j = 0; j < 4; ++j) bj[j] = bias[n0 + tx * 4 + j];

    #pragma unroll
    for (int h = 0; h < 2; ++h) {                  // row halves: ty*4 / 64+ty*4
        #pragma unroll
        for (int i = 0; i < 4; ++i) {
            const int mi = h * 4 + i;
            float* op = out + (size_t)(m0 + h * 64 + ty * 4 + i) * NDIM + n0 + tx * 4;
            float4 v;
            v.x = __fadd_rn(tot[mi][0], bj[0]);
            v.y = __fadd_rn(tot[mi][1], bj[1]);
            v.z = __fadd_rn(tot[mi][2], bj[2]);
            v.w = __fadd_rn(tot[mi][3], bj[3]);
            *(float4*)op = v;
        }
    }
}

// ===========================================================================
// f32 scan — byte-for-byte r16 (passed): 3-wave structure (producer /
// consumer / writer), consumer 6 libm bodies/step via select-before-log1p.
// ===========================================================================
__device__ __forceinline__ void gl_lds(const float* g, float* l) {
    __builtin_amdgcn_global_load_lds(
        (const __attribute__((address_space(1))) void*)g,
        (__attribute__((address_space(3))) void*)l, 4, 0, 0);
}

#define WAITVM(N) do {                                                   \
    asm volatile("s_waitcnt vmcnt(" #N ")" ::: "memory");                \
    __builtin_amdgcn_sched_barrier(0); } while (0)

__global__ __launch_bounds__(192, 1) void scan_kernel(
    float* __restrict__ log_h, float* __restrict__ sign_h, float* __restrict__ h_lin,
    const float* __restrict__ log_r_h, const float* __restrict__ sign_r_h)
{
    __shared__ float Xr[4][5][4][64];   // [slot][a,li,si,ld,lm][u][lane]  20 KB
    __shared__ float Or[4][2][4][64];   // [slot][lhn,shn][u][lane]         8 KB
    __shared__ float Rr[4][12][64];     // raw ring (producer only)        12 KB

    const int wv = threadIdx.x >> 6;
    const int ln = threadIdx.x & 63;
    const int idx = blockIdx.x * 64 + ln;

#define ISSUE_LOADS(GG, SL) do {                                         \
    const int _b = (GG) * 4;                                             \
    _Pragma("unroll")                                                    \
    for (int u = 0; u < 4; ++u) {                                        \
        gl_lds(h_lin  + (size_t)(_b + u) * BD + idx,     &Rr[SL][u * 3 + 0][0]); \
        gl_lds(log_h  + (size_t)(_b + u + 1) * BD + idx, &Rr[SL][u * 3 + 1][0]); \
        gl_lds(sign_h + (size_t)(_b + u + 1) * BD + idx, &Rr[SL][u * 3 + 2][0]); \
    } } while (0)

#define XFORM_TO(GG) do {                                                \
    const int _s = (GG) & 3;                                             \
    _Pragma("unroll")                                                    \
    for (int u = 0; u < 4; ++u) {                                        \
        const float araw = Rr[_s][u * 3 + 0][ln];                        \
        const float lin  = Rr[_s][u * 3 + 1][ln];                        \
        const float dr   = Rr[_s][u * 3 + 2][ln];                        \
        Xr[_s][0][u][ln] = __fadd_rn(1.0f, np_softplus(araw));           \
        const float ax = fabsf(lin);                                     \
        Xr[_s][1][u][ln] = (ax > 1e-10f) ? np_logf(fmaxf(ax, 1e-10f))    \
                                         : -40.0f;                       \
        Xr[_s][2][u][ln] = (lin < 0.0f) ? -1.0f : 1.0f;                  \
        const float e  = np_expf(-fabsf(dr));                            \
        const float l1 = np_log1pf(e);                                   \
        const float big = -__fadd_rn(fabsf(dr), l1);                     \
        const float sml = -l1;                                           \
        const float ld0 = (dr > 0.0f) ? sml : big;                       \
        const float lm0 = (dr > 0.0f) ? big : sml;                       \
        Xr[_s][3][u][ln] = (dr == 0.0f) ? -LOGE2F : ld0;                 \
        Xr[_s][4][u][ln] = (dr == 0.0f) ? -LOGE2F : lm0;                 \
    } } while (0)

#define WRITE_GROUP(GG) do {                                             \
    const int _s = (GG) & 3;                                             \
    _Pragma("unroll")                                                    \
    for (int u = 0; u < 4; ++u) {                                        \
        const int t = (GG) * 4 + u;                                      \
        const float lhn = Or[_s][0][u][ln];                              \
        const float shn = Or[_s][1][u][ln];                              \
        const float res = __fmul_rn(shn, np_expf(fminf(lhn, 20.0f)));    \
        const float h = (lhn > -39.0f) ? res : 0.0f;                     \
        log_h[(size_t)(t + 1) * BD + idx] = lhn;                         \
        sign_h[(size_t)(t + 1) * BD + idx] = shn;                        \
        h_lin[(size_t)t * BD + idx] = h;                                 \
    } } while (0)

    // ---- prologue ----
    float lrh = 0.0f, srh = 0.0f;
    if (wv == 1) {
        const int d = idx & 1023;
        lrh = log_r_h[d];
        srh = sign_r_h[d];
    } else if (wv == 0) {
        ISSUE_LOADS(0, 0);
        ISSUE_LOADS(1, 1);
        WAITVM(0);
        XFORM_TO(0);
        XFORM_TO(1);
        ISSUE_LOADS(2, 2);          // in flight across the barrier
    } else {
        log_h[idx] = -40.0f;        // row 0
        sign_h[idx] = 1.0f;
    }
    __syncthreads();

    float lhp = -40.0f, shp = 1.0f;

    for (int g = 0; g < 128; ++g) {
        if (wv == 0) {
            // FIFO before wait: loads(g+2)[12 old] | loads(g+3)[12 new]
            const int gl = (g + 3 < 128) ? g + 3 : 127;   // dead-slot clamp
            ISSUE_LOADS(gl, (g + 3) & 3);
            WAITVM(12);                                    // loads(g+2) done
            if (g + 2 < 128) XFORM_TO(g + 2);
        } else if (wv == 1) {
            const int s = g & 3;
            float xa[4], xli[4], xsi[4], xld[4], xlm[4];
            #pragma unroll
            for (int u = 0; u < 4; ++u) {
                xa[u]  = Xr[s][0][u][ln];
                xli[u] = Xr[s][1][u][ln];
                xsi[u] = Xr[s][2][u][ln];
                xld[u] = Xr[s][3][u][ln];
                xlm[u] = Xr[s][4][u][ln];
            }
            #pragma unroll
            for (int u = 0; u < 4; ++u) {       // serial chain (bit-frozen)
                const float log_rh  = __fadd_rn(lrh, lhp);
                const float sign_rh = __fmul_rn(srh, shp);
                float lv, sv;
                np_sla(log_rh, sign_rh, xli[u], xsi[u], lv, sv);
                const float tt = __fmul_rn(xa[u], lv);
                const float log_cand = -np_softplus(-tt);
                float lhn, shn;
                np_sla(__fadd_rn(xlm[u], lhp), shp,
                       __fadd_rn(xld[u], log_cand), sv, lhn, shn);
                Or[s][0][u][ln] = lhn;
                Or[s][1][u][ln] = shn;
                lhp = lhn; shp = shn;
            }
        } else {
            if (g > 0) WRITE_GROUP(g - 1);
        }
        __syncthreads();
    }
    if (wv == 2) WRITE_GROUP(127);   // last loop barrier orders Or[3]

#undef ISSUE_LOADS
#undef XFORM_TO
#undef WRITE_GROUP
}

// ===========================================================================
extern "C" void kernel_launch(void* const* d_in, const int* in_sizes, int n_in,
                              void* d_out, int out_size, void* d_ws, size_t ws_size,
                              hipStream_t stream) {
    const float* x        = (const float*)d_in[0];
    const float* W_x      = (const float*)d_in[1];
    const float* W_alpha  = (const float*)d_in[2];
    const float* W_delta  = (const float*)d_in[3];
    const float* b        = (const float*)d_in[4];
    const float* b_alpha  = (const float*)d_in[5];
    const float* b_delta  = (const float*)d_in[6];
    const float* log_r_h  = (const float*)d_in[7];
    const float* sign_r_h = (const float*)d_in[8];

    float* out    = (float*)d_out;
    float* log_h  = out;                            // [513, BD]
    float* sign_h = out + (size_t)513 * BD;         // [513, BD]
    float* h_lin  = out + (size_t)2 * 513 * BD;     // [512, BD]

    dim3 ggrid(GEMM_M / 128, NDIM / 64, 3);
    gemm_blas<<<ggrid, dim3(256), 0, stream>>>(
        x, W_alpha, W_x, W_delta, b_alpha, b, b_delta,
        h_lin, log_h + BD, sign_h + BD);

    scan_kernel<<<dim3(BD / 64), dim3(192), 0, stream>>>(
        log_h, sign_h, h_lin, log_r_h, sign_r_h);
}